// Round 4
// baseline (160.340 us; speedup 1.0000x reference)
//
#include <hip/hip_runtime.h>

// TT embedding gather, vocab 125000 = 50*50*50, emb 512 = 8*8*8.
// out[m,n,p] = sum_{r,s} g1[m,r] g2[r,n,s] g3[s,p]
// Stage 1: T[i2*50+i3][np][r] = sum_s g2[r,n,s] g3[s,p]  (transposed: lane's column contiguous)
// Stage 1b: counting-sort lookups by key=(table,pair) so same-pair lookups are adjacent;
//           XCD-chunked block swizzle puts each group on one XCD -> T slice L2/L1-resident.
// Stage 2: 1 wave per lookup: T column via 8x global_load_dwordx4, g1 via s_load_dwordx16,
//          pure v_fmac_f32 inner loop. No LDS, no barriers.

#define NFAC 50
#define TPAIR 2048
#define NPAIRS 2500
#define NKEYS 5000
#define NWORD 8192
#define NCTX  81920
#define NLOOK (NWORD + NCTX)

typedef float f16v __attribute__((ext_vector_type(16)));

__device__ __forceinline__ const float* uptr(const float* p) {
    unsigned long long v = (unsigned long long)p;
    unsigned lo = __builtin_amdgcn_readfirstlane((unsigned)v);
    unsigned hi = __builtin_amdgcn_readfirstlane((unsigned)(v >> 32));
    return (const float*)(((unsigned long long)hi << 32) | lo);
}

__device__ __forceinline__ int pair_of(int idx) {
    const int i3 = idx % NFAC;
    const int i2 = (idx / NFAC) % NFAC;
    return i2 * NFAC + i3;
}

// ---------------- sort: zero / hist / scan / scatter ----------------

__global__ __launch_bounds__(256) void tt_zero(int* __restrict__ hist) {
    const int g = blockIdx.x * 256 + threadIdx.x;
    if (g < NKEYS) hist[g] = 0;
}

__global__ __launch_bounds__(256) void tt_hist(
    const int* __restrict__ widx, const int* __restrict__ cidx, int* __restrict__ hist)
{
    const int g = blockIdx.x * 256 + threadIdx.x;
    if (g >= NLOOK) return;
    const int idx = (g < NWORD) ? widx[g] : cidx[g - NWORD];
    const int key = (g < NWORD ? 0 : NPAIRS) + pair_of(idx);
    atomicAdd(&hist[key], 1);
}

__global__ __launch_bounds__(1024) void tt_scan(
    const int* __restrict__ hist, int* __restrict__ offs)
{
    __shared__ int tmp[1024];
    __shared__ int carry_s;
    const int t = threadIdx.x;
    if (t == 0) carry_s = 0;
    __syncthreads();
    for (int c = 0; c < 5; ++c) {            // 5*1024 >= 5000
        const int i = c * 1024 + t;
        const int v = (i < NKEYS) ? hist[i] : 0;
        tmp[t] = v;
        __syncthreads();
        int acc = v;
        for (int o = 1; o < 1024; o <<= 1) {
            const int x = (t >= o) ? tmp[t - o] : 0;
            __syncthreads();
            acc += x; tmp[t] = acc;
            __syncthreads();
        }
        if (i < NKEYS) offs[i] = carry_s + acc - v;   // exclusive prefix
        __syncthreads();
        if (t == 1023) carry_s += acc;                // acc = chunk total here
        __syncthreads();
    }
}

__global__ __launch_bounds__(256) void tt_scatter(
    const int* __restrict__ widx, const int* __restrict__ cidx,
    int* __restrict__ offs, int* __restrict__ sorted)
{
    const int g = blockIdx.x * 256 + threadIdx.x;
    if (g >= NLOOK) return;
    const int idx = (g < NWORD) ? widx[g] : cidx[g - NWORD];
    const int key = (g < NWORD ? 0 : NPAIRS) + pair_of(idx);
    const int pos = atomicAdd(&offs[key], 1);
    sorted[pos] = g;
}

// ---------------- stage 1: T precompute (transposed [pair][np][r]) ----------------

__global__ __launch_bounds__(256) void tt_precompute(
    const float* __restrict__ w2, const float* __restrict__ w3,
    const float* __restrict__ c2, const float* __restrict__ c3,
    float* __restrict__ Tw, float* __restrict__ Tc)
{
    int pair = blockIdx.x;
    const float* core2; const float* core3; float* T;
    if (pair < NPAIRS) { core2 = w2; core3 = w3; T = Tw; }
    else { pair -= NPAIRS; core2 = c2; core3 = c3; T = Tc; }
    const int i2 = pair / NFAC, i3 = pair % NFAC;
    __shared__ float g3s[256];                   // g3[s][p], s major
    const int t = threadIdx.x;
    g3s[t] = core3[i3 * 256 + t];
    __syncthreads();
    const int r = t >> 3, n = t & 7;
    const float* g2row = core2 + i2 * 8192 + r * 256 + n * 32;
    float acc[8] = {0.f,0.f,0.f,0.f,0.f,0.f,0.f,0.f};
    #pragma unroll
    for (int s4 = 0; s4 < 8; ++s4) {
        const float4 v = reinterpret_cast<const float4*>(g2row)[s4];
        const float vv[4] = {v.x, v.y, v.z, v.w};
        #pragma unroll
        for (int j = 0; j < 4; ++j) {
            const int s = s4 * 4 + j;
            #pragma unroll
            for (int p = 0; p < 8; ++p)
                acc[p] += vv[j] * g3s[s * 8 + p];
        }
    }
    float* dst = T + (size_t)pair * TPAIR;       // layout [np][r]
    #pragma unroll
    for (int p = 0; p < 8; ++p)
        dst[(n * 8 + p) * 32 + r] = acc[p];
}

// ---------------- stage 2: lookup, 1 wave per lookup, zero LDS ----------------

__global__ __launch_bounds__(256, 8) void tt_lookup(
    const int* __restrict__ sorted,              // may be null (identity order)
    const int* __restrict__ word_idx, const int* __restrict__ ctx_idx,
    const float* __restrict__ w_core1, const float* __restrict__ c_core1,
    const float* __restrict__ Tw, const float* __restrict__ Tc,
    float* __restrict__ out)
{
    const int wave = threadIdx.x >> 6;
    const int lane = threadIdx.x & 63;
    const int nwg = NLOOK / 4;                   // 22528, divisible by 8
    const int B = blockIdx.x;
    const int sb = (B & 7) * (nwg >> 3) + (B >> 3);   // XCD-chunked bijective swizzle
    const int spos = sb * 4 + wave;

    int lid = spos;
    if (sorted) lid = __builtin_amdgcn_readfirstlane(sorted[spos]);

    int vidx; const float* core1; const float* T;
    if (lid < NWORD) { vidx = word_idx[lid]; core1 = w_core1; T = Tw; }
    else             { vidx = ctx_idx[lid - NWORD]; core1 = c_core1; T = Tc; }
    const int idx = __builtin_amdgcn_readfirstlane(vidx);
    const int i3  = idx % NFAC;
    const int rem = idx / NFAC;
    const int i2  = rem % NFAC;
    const int i1  = rem / NFAC;

    const float* Ts  = uptr(T + (size_t)(i2 * NFAC + i3) * TPAIR);
    const float* g1p = uptr(core1 + i1 * 256);

    // lane's T column: 32 contiguous floats -> 8x global_load_dwordx4
    float t[32];
    {
        const float4* Tq = reinterpret_cast<const float4*>(Ts + lane * 32);
        #pragma unroll
        for (int k = 0; k < 8; ++k) {
            const float4 v = Tq[k];
            t[4*k+0] = v.x; t[4*k+1] = v.y; t[4*k+2] = v.z; t[4*k+3] = v.w;
        }
    }

    float* o = out + (size_t)lid * 512 + lane;

    #pragma unroll
    for (int mp = 0; mp < 4; ++mp) {             // two m-rows per iter
        f16v g0, g1, g2, g3;
        asm volatile(
            "s_load_dwordx16 %0, %4, %5\n\t"
            "s_load_dwordx16 %1, %4, %6\n\t"
            "s_load_dwordx16 %2, %4, %7\n\t"
            "s_load_dwordx16 %3, %4, %8"
            : "=&s"(g0), "=&s"(g1), "=&s"(g2), "=&s"(g3)
            : "s"(g1p), "i"(mp * 256), "i"(mp * 256 + 64),
              "i"(mp * 256 + 128), "i"(mp * 256 + 192));
        asm volatile("s_waitcnt lgkmcnt(0)"
                     : "+s"(g0), "+s"(g1), "+s"(g2), "+s"(g3));
        float a0 = 0.f, b0 = 0.f, a1 = 0.f, b1 = 0.f;
        #pragma unroll
        for (int r = 0; r < 16; ++r) {
            a0 += g0[r] * t[r];
            b0 += g1[r] * t[16 + r];
            a1 += g2[r] * t[r];
            b1 += g3[r] * t[16 + r];
        }
        o[(2 * mp)     * 64] = a0 + b0;
        o[(2 * mp + 1) * 64] = a1 + b1;
    }
}

// ---------------- fallback (ws too small for T tables) ----------------

__global__ __launch_bounds__(512) void tt_fused(
    const int* __restrict__ word_idx, const int* __restrict__ ctx_idx,
    const float* __restrict__ w1, const float* __restrict__ w2, const float* __restrict__ w3,
    const float* __restrict__ c1, const float* __restrict__ c2, const float* __restrict__ c3,
    float* __restrict__ out)
{
    const int b = blockIdx.x;
    int idx; const float *k1, *k2, *k3; float* o;
    if (b < NWORD) { idx = word_idx[b]; k1 = w1; k2 = w2; k3 = w3; o = out + (size_t)b * 512; }
    else { const int c = b - NWORD; idx = ctx_idx[c]; k1 = c1; k2 = c2; k3 = c3;
           o = out + (size_t)(NWORD + c) * 512; }
    const int i3 = idx % NFAC;
    const int rem = idx / NFAC;
    const int i2 = rem % NFAC;
    const int i1 = rem / NFAC;

    __shared__ float g3s[256];
    __shared__ float g1s[256];
    __shared__ float Ts[TPAIR];
    const int t = threadIdx.x;
    if (t < 256) g3s[t] = k3[i3 * 256 + t];
    else         g1s[t - 256] = k1[i1 * 256 + (t - 256)];
    __syncthreads();

    {
        const int e0 = t * 4;
        const int r = e0 >> 6, n = (e0 >> 3) & 7, p0 = e0 & 7;
        const float* g2row = k2 + i2 * 8192 + r * 256 + n * 32;
        float acc[4] = {0.f,0.f,0.f,0.f};
        #pragma unroll
        for (int s = 0; s < 32; ++s) {
            const float v = g2row[s];
            #pragma unroll
            for (int j = 0; j < 4; ++j) acc[j] += v * g3s[s * 8 + p0 + j];
        }
        reinterpret_cast<float4*>(Ts + e0)[0] = make_float4(acc[0], acc[1], acc[2], acc[3]);
    }
    __syncthreads();

    const int m = t >> 6, np = t & 63;
    float acc = 0.f;
    #pragma unroll
    for (int r = 0; r < 32; ++r)
        acc += g1s[m * 32 + r] * Ts[r * 64 + np];
    o[m * 64 + np] = acc;
}

extern "C" void kernel_launch(void* const* d_in, const int* in_sizes, int n_in,
                              void* d_out, int out_size, void* d_ws, size_t ws_size,
                              hipStream_t stream) {
    const int*   widx = (const int*)d_in[0];
    const int*   cidx = (const int*)d_in[1];
    const float* w1   = (const float*)d_in[2];
    const float* w2   = (const float*)d_in[3];
    const float* w3   = (const float*)d_in[4];
    const float* c1   = (const float*)d_in[5];
    const float* c2   = (const float*)d_in[6];
    const float* c3   = (const float*)d_in[7];
    float* out = (float*)d_out;

    const size_t t_elems   = (size_t)NPAIRS * TPAIR;
    const size_t t_bytes   = 2 * t_elems * sizeof(float);
    const size_t sort_bytes = (size_t)(2 * NKEYS + NLOOK) * sizeof(int);

    if (ws_size >= t_bytes + sort_bytes) {
        float* Tw   = (float*)d_ws;
        float* Tc   = Tw + t_elems;
        int* hist   = (int*)(Tc + t_elems);
        int* offs   = hist + NKEYS;
        int* sorted = offs + NKEYS;
        tt_zero<<<(NKEYS + 255) / 256, 256, 0, stream>>>(hist);
        tt_hist<<<(NLOOK + 255) / 256, 256, 0, stream>>>(widx, cidx, hist);
        tt_scan<<<1, 1024, 0, stream>>>(hist, offs);
        tt_scatter<<<(NLOOK + 255) / 256, 256, 0, stream>>>(widx, cidx, offs, sorted);
        tt_precompute<<<2 * NPAIRS, 256, 0, stream>>>(w2, w3, c2, c3, Tw, Tc);
        tt_lookup<<<NLOOK / 4, 256, 0, stream>>>(sorted, widx, cidx, w1, c1, Tw, Tc, out);
    } else if (ws_size >= t_bytes) {
        float* Tw = (float*)d_ws;
        float* Tc = Tw + t_elems;
        tt_precompute<<<2 * NPAIRS, 256, 0, stream>>>(w2, w3, c2, c3, Tw, Tc);
        tt_lookup<<<NLOOK / 4, 256, 0, stream>>>(nullptr, widx, cidx, w1, c1, Tw, Tc, out);
    } else {
        tt_fused<<<NLOOK, 512, 0, stream>>>(widx, cidx, w1, w2, w3, c1, c2, c3, out);
    }
}

// Round 5
// 126.493 us; speedup vs baseline: 1.2676x; 1.2676x over previous
//
#include <hip/hip_runtime.h>

// TT embedding gather, vocab 125000 = 50*50*50, emb 512 = 8*8*8.
// out[m,n,p] = sum_{r,s} g1[m,r] g2[r,n,s] g3[s,p]
// Stage 1: T[i2*50+i3][r][np] = sum_s g2[r,n,s] g3[s,p]   (2500 pairs x 2048 floats per table)
// Stage 1b: counting-group lookups by key=(table,pair): hist -> shuffle-scan -> scatter.
// Stage 2: tt_group — one block per key. Each wave loads its T column slice ONCE into
//          32 VGPRs, then loops the group's lookups: g1 via s_load_dwordx16 (SGPRs),
//          256 v_fmac, 8 coalesced stores. T is never re-fetched per lookup.

#define NFAC 50
#define TPAIR 2048
#define NPAIRS 2500
#define NKEYS 5000
#define NWORD 8192
#define NCTX  81920
#define NLOOK (NWORD + NCTX)

typedef float f16v __attribute__((ext_vector_type(16)));

__device__ __forceinline__ const float* uptr(const float* p) {
    unsigned long long v = (unsigned long long)p;
    unsigned lo = __builtin_amdgcn_readfirstlane((unsigned)v);
    unsigned hi = __builtin_amdgcn_readfirstlane((unsigned)(v >> 32));
    return (const float*)(((unsigned long long)hi << 32) | lo);
}

__device__ __forceinline__ int pair_of(int idx) {
    const int i3 = idx % NFAC;
    const int i2 = (idx / NFAC) % NFAC;
    return i2 * NFAC + i3;
}

// ---------------- grouping: zero / hist / scan / scatter ----------------

__global__ __launch_bounds__(256) void tt_zero(int* __restrict__ hist) {
    const int g = blockIdx.x * 256 + threadIdx.x;
    if (g < NKEYS) hist[g] = 0;
}

__global__ __launch_bounds__(256) void tt_hist(
    const int* __restrict__ widx, const int* __restrict__ cidx, int* __restrict__ hist)
{
    const int g = blockIdx.x * 256 + threadIdx.x;
    if (g >= NLOOK) return;
    const int idx = (g < NWORD) ? widx[g] : cidx[g - NWORD];
    const int key = (g < NWORD ? 0 : NPAIRS) + pair_of(idx);
    atomicAdd(&hist[key], 1);
}

// Single-block exclusive scan of 5000 ints: 5/thread + wave shfl-scan + cross-wave LDS.
__global__ __launch_bounds__(1024) void tt_scan(
    const int* __restrict__ hist, int* __restrict__ offs, int* __restrict__ cursor)
{
    const int t = threadIdx.x;
    const int lane = t & 63, wid = t >> 6;           // 16 waves
    const int base = t * 5;
    int v[5]; int s = 0;
    #pragma unroll
    for (int j = 0; j < 5; ++j) { v[j] = (base + j < NKEYS) ? hist[base + j] : 0; s += v[j]; }
    int incl = s;                                     // inclusive wave scan
    #pragma unroll
    for (int o = 1; o < 64; o <<= 1) {
        const int x = __shfl_up(incl, o, 64);
        if (lane >= o) incl += x;
    }
    __shared__ int wsum[16];
    __shared__ int woff[16];
    if (lane == 63) wsum[wid] = incl;
    __syncthreads();
    if (t == 0) {
        int acc = 0;
        for (int w = 0; w < 16; ++w) { const int x = wsum[w]; woff[w] = acc; acc += x; }
    }
    __syncthreads();
    int excl = woff[wid] + (incl - s);
    #pragma unroll
    for (int j = 0; j < 5; ++j) {
        if (base + j < NKEYS) { offs[base + j] = excl; cursor[base + j] = excl; }
        excl += v[j];
    }
}

__global__ __launch_bounds__(256) void tt_scatter(
    const int* __restrict__ widx, const int* __restrict__ cidx,
    int* __restrict__ cursor, int* __restrict__ grouped)
{
    const int g = blockIdx.x * 256 + threadIdx.x;
    if (g >= NLOOK) return;
    const int idx = (g < NWORD) ? widx[g] : cidx[g - NWORD];
    const int key = (g < NWORD ? 0 : NPAIRS) + pair_of(idx);
    const int pos = atomicAdd(&cursor[key], 1);
    grouped[pos] = g;
}

// ---------------- stage 1: T precompute, layout [pair][r][np] ----------------

__global__ __launch_bounds__(256) void tt_precompute(
    const float* __restrict__ w2, const float* __restrict__ w3,
    const float* __restrict__ c2, const float* __restrict__ c3,
    float* __restrict__ Tw, float* __restrict__ Tc)
{
    int pair = blockIdx.x;
    const float* core2; const float* core3; float* T;
    if (pair < NPAIRS) { core2 = w2; core3 = w3; T = Tw; }
    else { pair -= NPAIRS; core2 = c2; core3 = c3; T = Tc; }
    const int i2 = pair / NFAC, i3 = pair % NFAC;
    __shared__ float g3s[256];                   // g3[s][p], s major
    const int t = threadIdx.x;
    g3s[t] = core3[i3 * 256 + t];
    __syncthreads();
    const int r = t >> 3, n = t & 7;
    const float* g2row = core2 + i2 * 8192 + r * 256 + n * 32;
    float acc[8] = {0.f,0.f,0.f,0.f,0.f,0.f,0.f,0.f};
    #pragma unroll
    for (int s4 = 0; s4 < 8; ++s4) {
        const float4 v = reinterpret_cast<const float4*>(g2row)[s4];
        const float vv[4] = {v.x, v.y, v.z, v.w};
        #pragma unroll
        for (int j = 0; j < 4; ++j) {
            const int s = s4 * 4 + j;
            #pragma unroll
            for (int p = 0; p < 8; ++p)
                acc[p] += vv[j] * g3s[s * 8 + p];
        }
    }
    float* dst = T + (size_t)pair * TPAIR + t * 8;   // [r][n][p] = [r][np]
    reinterpret_cast<float4*>(dst)[0] = make_float4(acc[0], acc[1], acc[2], acc[3]);
    reinterpret_cast<float4*>(dst)[1] = make_float4(acc[4], acc[5], acc[6], acc[7]);
}

// ---------------- stage 2: one block per key, T in VGPRs across the group ----------------

__global__ __launch_bounds__(256, 8) void tt_group(
    const int* __restrict__ grouped, const int* __restrict__ hist,
    const int* __restrict__ offs,
    const int* __restrict__ word_idx, const int* __restrict__ ctx_idx,
    const float* __restrict__ w_core1, const float* __restrict__ c_core1,
    const float* __restrict__ Tw, const float* __restrict__ Tc,
    float* __restrict__ out)
{
    const int key = blockIdx.x;
    const int count = hist[key];
    if (count == 0) return;
    const int base = offs[key];
    const int wave = threadIdx.x >> 6;
    const int lane = threadIdx.x & 63;

    const bool isCtx = key >= NPAIRS;
    const int pair = isCtx ? key - NPAIRS : key;
    const float* T = isCtx ? Tc : Tw;
    const float* core1 = isCtx ? c_core1 : w_core1;
    const float* Ts = uptr(T + (size_t)pair * TPAIR);

    // Wave's T slice -> 32 VGPRs, loaded once (waves 1-3 hit L1).
    float t[32];
    #pragma unroll
    for (int r = 0; r < 32; ++r) t[r] = Ts[r * 64 + lane];

    for (int j = wave; j < count; j += 4) {
        const int lid = __builtin_amdgcn_readfirstlane(grouped[base + j]);
        const int vidx = (lid < NWORD) ? word_idx[lid] : ctx_idx[lid - NWORD];
        const int idx = __builtin_amdgcn_readfirstlane(vidx);
        const int i1 = idx / (NFAC * NFAC);
        const float* g1p = uptr(core1 + i1 * 256);
        float* o = out + (size_t)lid * 512 + lane;

        #pragma unroll
        for (int mp = 0; mp < 4; ++mp) {             // two m-rows per iter
            f16v g0, g1, g2, g3;
            asm volatile(
                "s_load_dwordx16 %0, %4, %5\n\t"
                "s_load_dwordx16 %1, %4, %6\n\t"
                "s_load_dwordx16 %2, %4, %7\n\t"
                "s_load_dwordx16 %3, %4, %8"
                : "=&s"(g0), "=&s"(g1), "=&s"(g2), "=&s"(g3)
                : "s"(g1p), "i"(mp * 256), "i"(mp * 256 + 64),
                  "i"(mp * 256 + 128), "i"(mp * 256 + 192));
            asm volatile("s_waitcnt lgkmcnt(0)"
                         : "+s"(g0), "+s"(g1), "+s"(g2), "+s"(g3));
            float a0 = 0.f, b0 = 0.f, a1 = 0.f, b1 = 0.f;
            #pragma unroll
            for (int r = 0; r < 16; ++r) {
                a0 += g0[r] * t[r];
                b0 += g1[r] * t[16 + r];
                a1 += g2[r] * t[r];
                b1 += g3[r] * t[16 + r];
            }
            o[(2 * mp)     * 64] = a0 + b0;
            o[(2 * mp + 1) * 64] = a1 + b1;
        }
    }
}

// ---------------- fallback: unsorted 1-wave-per-lookup (mid ws) ----------------

__global__ __launch_bounds__(256, 8) void tt_lookup(
    const int* __restrict__ word_idx, const int* __restrict__ ctx_idx,
    const float* __restrict__ w_core1, const float* __restrict__ c_core1,
    const float* __restrict__ Tw, const float* __restrict__ Tc,
    float* __restrict__ out)
{
    const int wave = threadIdx.x >> 6;
    const int lane = threadIdx.x & 63;
    const int look = blockIdx.x * 4 + wave;

    int vidx; const float* core1; const float* T;
    if (look < NWORD) { vidx = word_idx[look]; core1 = w_core1; T = Tw; }
    else              { vidx = ctx_idx[look - NWORD]; core1 = c_core1; T = Tc; }
    const int idx = __builtin_amdgcn_readfirstlane(vidx);
    const int i3  = idx % NFAC;
    const int rem = idx / NFAC;
    const int i2  = rem % NFAC;
    const int i1  = rem / NFAC;

    const float* Ts  = uptr(T + (size_t)(i2 * NFAC + i3) * TPAIR);
    const float* g1p = uptr(core1 + i1 * 256);

    float t[32];
    #pragma unroll
    for (int r = 0; r < 32; ++r) t[r] = Ts[r * 64 + lane];

    float* o = out + (size_t)look * 512 + lane;

    #pragma unroll
    for (int mp = 0; mp < 4; ++mp) {
        f16v g0, g1, g2, g3;
        asm volatile(
            "s_load_dwordx16 %0, %4, %5\n\t"
            "s_load_dwordx16 %1, %4, %6\n\t"
            "s_load_dwordx16 %2, %4, %7\n\t"
            "s_load_dwordx16 %3, %4, %8"
            : "=&s"(g0), "=&s"(g1), "=&s"(g2), "=&s"(g3)
            : "s"(g1p), "i"(mp * 256), "i"(mp * 256 + 64),
              "i"(mp * 256 + 128), "i"(mp * 256 + 192));
        asm volatile("s_waitcnt lgkmcnt(0)"
                     : "+s"(g0), "+s"(g1), "+s"(g2), "+s"(g3));
        float a0 = 0.f, b0 = 0.f, a1 = 0.f, b1 = 0.f;
        #pragma unroll
        for (int r = 0; r < 16; ++r) {
            a0 += g0[r] * t[r];
            b0 += g1[r] * t[16 + r];
            a1 += g2[r] * t[r];
            b1 += g3[r] * t[16 + r];
        }
        o[(2 * mp)     * 64] = a0 + b0;
        o[(2 * mp + 1) * 64] = a1 + b1;
    }
}

// ---------------- fallback: fully fused (tiny ws) ----------------

__global__ __launch_bounds__(512) void tt_fused(
    const int* __restrict__ word_idx, const int* __restrict__ ctx_idx,
    const float* __restrict__ w1, const float* __restrict__ w2, const float* __restrict__ w3,
    const float* __restrict__ c1, const float* __restrict__ c2, const float* __restrict__ c3,
    float* __restrict__ out)
{
    const int b = blockIdx.x;
    int idx; const float *k1, *k2, *k3; float* o;
    if (b < NWORD) { idx = word_idx[b]; k1 = w1; k2 = w2; k3 = w3; o = out + (size_t)b * 512; }
    else { const int c = b - NWORD; idx = ctx_idx[c]; k1 = c1; k2 = c2; k3 = c3;
           o = out + (size_t)(NWORD + c) * 512; }
    const int i3 = idx % NFAC;
    const int rem = idx / NFAC;
    const int i2 = rem % NFAC;
    const int i1 = rem / NFAC;

    __shared__ float g3s[256];
    __shared__ float g1s[256];
    __shared__ float Ts[TPAIR];
    const int t = threadIdx.x;
    if (t < 256) g3s[t] = k3[i3 * 256 + t];
    else         g1s[t - 256] = k1[i1 * 256 + (t - 256)];
    __syncthreads();

    {
        const int e0 = t * 4;
        const int r = e0 >> 6, n = (e0 >> 3) & 7, p0 = e0 & 7;
        const float* g2row = k2 + i2 * 8192 + r * 256 + n * 32;
        float acc[4] = {0.f,0.f,0.f,0.f};
        #pragma unroll
        for (int s = 0; s < 32; ++s) {
            const float v = g2row[s];
            #pragma unroll
            for (int j = 0; j < 4; ++j) acc[j] += v * g3s[s * 8 + p0 + j];
        }
        reinterpret_cast<float4*>(Ts + e0)[0] = make_float4(acc[0], acc[1], acc[2], acc[3]);
    }
    __syncthreads();

    const int m = t >> 6, np = t & 63;
    float acc = 0.f;
    #pragma unroll
    for (int r = 0; r < 32; ++r)
        acc += g1s[m * 32 + r] * Ts[r * 64 + np];
    o[m * 64 + np] = acc;
}

extern "C" void kernel_launch(void* const* d_in, const int* in_sizes, int n_in,
                              void* d_out, int out_size, void* d_ws, size_t ws_size,
                              hipStream_t stream) {
    const int*   widx = (const int*)d_in[0];
    const int*   cidx = (const int*)d_in[1];
    const float* w1   = (const float*)d_in[2];
    const float* w2   = (const float*)d_in[3];
    const float* w3   = (const float*)d_in[4];
    const float* c1   = (const float*)d_in[5];
    const float* c2   = (const float*)d_in[6];
    const float* c3   = (const float*)d_in[7];
    float* out = (float*)d_out;

    const size_t t_elems    = (size_t)NPAIRS * TPAIR;
    const size_t t_bytes    = 2 * t_elems * sizeof(float);
    const size_t sort_bytes = (size_t)(3 * NKEYS + NLOOK) * sizeof(int);

    if (ws_size >= t_bytes + sort_bytes) {
        float* Tw    = (float*)d_ws;
        float* Tc    = Tw + t_elems;
        int* hist    = (int*)(Tc + t_elems);
        int* offs    = hist + NKEYS;
        int* cursor  = offs + NKEYS;
        int* grouped = cursor + NKEYS;
        tt_zero<<<(NKEYS + 255) / 256, 256, 0, stream>>>(hist);
        tt_hist<<<(NLOOK + 255) / 256, 256, 0, stream>>>(widx, cidx, hist);
        tt_scan<<<1, 1024, 0, stream>>>(hist, offs, cursor);
        tt_scatter<<<(NLOOK + 255) / 256, 256, 0, stream>>>(widx, cidx, cursor, grouped);
        tt_precompute<<<2 * NPAIRS, 256, 0, stream>>>(w2, w3, c2, c3, Tw, Tc);
        tt_group<<<NKEYS, 256, 0, stream>>>(grouped, hist, offs, widx, cidx,
                                            w1, c1, Tw, Tc, out);
    } else if (ws_size >= t_bytes) {
        float* Tw = (float*)d_ws;
        float* Tc = Tw + t_elems;
        tt_precompute<<<2 * NPAIRS, 256, 0, stream>>>(w2, w3, c2, c3, Tw, Tc);
        tt_lookup<<<NLOOK / 4, 256, 0, stream>>>(widx, cidx, w1, c1, Tw, Tc, out);
    } else {
        tt_fused<<<NLOOK, 512, 0, stream>>>(widx, cidx, w1, w2, w3, c1, c2, c3, out);
    }
}

// Round 6
// 100.342 us; speedup vs baseline: 1.5979x; 1.2606x over previous
//
#include <hip/hip_runtime.h>

// TT embedding gather, vocab 125000 = 50*50*50, emb 512 = 8*8*8.
// out[m,n,p] = sum_{r,s} g1[m,r] g2[r,n,s] g3[s,p]
// Stage 1: group lookups by key=(table, i2*50+i3): hist -> scan -> scatter.
// Stage 2: Tbf[key][r][np] = sum_s g2[r,n,s] g3[s,p], stored as bf16 in MFMA
//          B-fragment layout; g1 tables converted to bf16.
// Stage 3: tt_group_mfma — one block (4 waves) per key. B-frags (T slice) loaded once
//          into 16 VGPRs; per tile (2 lookups) one dwordx4/lane A-load (g1 rows) and
//          4x mfma_f32_16x16x32_bf16; f32 results stored coalesced.
//          out rows: D col=lane&15 (np within 16-block), D row=(lane>>4)*4+reg
//          = (lookup, m).  [m89-verified C/D mapping]

#define NFAC 50
#define TPAIR 2048
#define NPAIRS 2500
#define NKEYS 5000
#define NWORD 8192
#define NCTX  81920
#define NLOOK (NWORD + NCTX)

typedef short short8 __attribute__((ext_vector_type(8)));   // 8 bf16 (4 VGPRs)
typedef float f32x4v __attribute__((ext_vector_type(4)));

typedef float f16v __attribute__((ext_vector_type(16)));

__device__ __forceinline__ unsigned short f2bf(float f) {   // RNE f32 -> bf16 bits
    unsigned u = __builtin_bit_cast(unsigned, f);
    u += 0x7FFFu + ((u >> 16) & 1u);
    return (unsigned short)(u >> 16);
}

__device__ __forceinline__ const float* uptr(const float* p) {
    unsigned long long v = (unsigned long long)p;
    unsigned lo = __builtin_amdgcn_readfirstlane((unsigned)v);
    unsigned hi = __builtin_amdgcn_readfirstlane((unsigned)(v >> 32));
    return (const float*)(((unsigned long long)hi << 32) | lo);
}

__device__ __forceinline__ int pair_of(int idx) {
    const int i3 = idx % NFAC;
    const int i2 = (idx / NFAC) % NFAC;
    return i2 * NFAC + i3;
}

// ---------------- grouping: zero / hist / scan / scatter ----------------

__global__ __launch_bounds__(256) void tt_zero(int* __restrict__ hist) {
    const int g = blockIdx.x * 256 + threadIdx.x;
    if (g < NKEYS) hist[g] = 0;
}

__global__ __launch_bounds__(256) void tt_hist(
    const int* __restrict__ widx, const int* __restrict__ cidx, int* __restrict__ hist)
{
    const int g = blockIdx.x * 256 + threadIdx.x;
    if (g >= NLOOK) return;
    const int idx = (g < NWORD) ? widx[g] : cidx[g - NWORD];
    const int key = (g < NWORD ? 0 : NPAIRS) + pair_of(idx);
    atomicAdd(&hist[key], 1);
}

// Single-block exclusive scan of 5000 ints: 5/thread + wave shfl-scan + cross-wave LDS.
__global__ __launch_bounds__(1024) void tt_scan(
    const int* __restrict__ hist, int* __restrict__ offs, int* __restrict__ cursor)
{
    const int t = threadIdx.x;
    const int lane = t & 63, wid = t >> 6;           // 16 waves
    const int base = t * 5;
    int v[5]; int s = 0;
    #pragma unroll
    for (int j = 0; j < 5; ++j) { v[j] = (base + j < NKEYS) ? hist[base + j] : 0; s += v[j]; }
    int incl = s;
    #pragma unroll
    for (int o = 1; o < 64; o <<= 1) {
        const int x = __shfl_up(incl, o, 64);
        if (lane >= o) incl += x;
    }
    __shared__ int wsum[16];
    __shared__ int woff[16];
    if (lane == 63) wsum[wid] = incl;
    __syncthreads();
    if (t == 0) {
        int acc = 0;
        for (int w = 0; w < 16; ++w) { const int x = wsum[w]; woff[w] = acc; acc += x; }
    }
    __syncthreads();
    int excl = woff[wid] + (incl - s);
    #pragma unroll
    for (int j = 0; j < 5; ++j) {
        if (base + j < NKEYS) { offs[base + j] = excl; cursor[base + j] = excl; }
        excl += v[j];
    }
}

__global__ __launch_bounds__(256) void tt_scatter(
    const int* __restrict__ widx, const int* __restrict__ cidx,
    int* __restrict__ cursor, int* __restrict__ grouped)
{
    const int g = blockIdx.x * 256 + threadIdx.x;
    if (g >= NLOOK) return;
    const int idx = (g < NWORD) ? widx[g] : cidx[g - NWORD];
    const int key = (g < NWORD ? 0 : NPAIRS) + pair_of(idx);
    const int pos = atomicAdd(&cursor[key], 1);
    grouped[pos] = g;
}

// ---------------- bf16 conversion of g1 tables ----------------

__global__ __launch_bounds__(256) void tt_cvt_g1(
    const float* __restrict__ w1, const float* __restrict__ c1,
    unsigned short* __restrict__ g1w, unsigned short* __restrict__ g1c)
{
    const int g = blockIdx.x * 256 + threadIdx.x;     // 2 x 12800
    if (g < 12800) g1w[g] = f2bf(w1[g]);
    else if (g < 25600) g1c[g - 12800] = f2bf(c1[g - 12800]);
}

// ---------------- T precompute -> bf16 in B-fragment layout ----------------
// B-frag: lane l of frag npg holds B[k=8*(l>>4)+j][col=npg*16+(l&15)], j=0..7.
// flat(np, r) = (np>>4)*512 + ((r>>3)*16 + (np&15))*8 + (r&7)

__global__ __launch_bounds__(256) void tt_precompute_bf(
    const float* __restrict__ w2, const float* __restrict__ w3,
    const float* __restrict__ c2, const float* __restrict__ c3,
    unsigned short* __restrict__ Tw, unsigned short* __restrict__ Tc)
{
    int pair = blockIdx.x;
    const float* core2; const float* core3; unsigned short* T;
    if (pair < NPAIRS) { core2 = w2; core3 = w3; T = Tw; }
    else { pair -= NPAIRS; core2 = c2; core3 = c3; T = Tc; }
    const int i2 = pair / NFAC, i3 = pair % NFAC;
    __shared__ float g3s[256];                   // g3[s][p]
    const int t = threadIdx.x;
    g3s[t] = core3[i3 * 256 + t];
    __syncthreads();
    const int r = t >> 3, n = t & 7;
    const float* g2row = core2 + i2 * 8192 + r * 256 + n * 32;
    float acc[8] = {0.f,0.f,0.f,0.f,0.f,0.f,0.f,0.f};
    #pragma unroll
    for (int s4 = 0; s4 < 8; ++s4) {
        const float4 v = reinterpret_cast<const float4*>(g2row)[s4];
        const float vv[4] = {v.x, v.y, v.z, v.w};
        #pragma unroll
        for (int j = 0; j < 4; ++j) {
            const int s = s4 * 4 + j;
            #pragma unroll
            for (int p = 0; p < 8; ++p)
                acc[p] += vv[j] * g3s[s * 8 + p];
        }
    }
    unsigned short* dst = T + (size_t)pair * TPAIR;
    #pragma unroll
    for (int p = 0; p < 8; ++p) {
        const int np = n * 8 + p;
        const int flat = (np >> 4) * 512 + ((r >> 3) * 16 + (np & 15)) * 8 + (r & 7);
        dst[flat] = f2bf(acc[p]);
    }
}

// ---------------- stage 3: MFMA group kernel ----------------

__global__ __launch_bounds__(256, 8) void tt_group_mfma(
    const int* __restrict__ grouped, const int* __restrict__ hist,
    const int* __restrict__ offs,
    const int* __restrict__ widx, const int* __restrict__ cidx,
    const unsigned short* __restrict__ g1w, const unsigned short* __restrict__ g1c,
    const unsigned short* __restrict__ Tw, const unsigned short* __restrict__ Tc,
    float* __restrict__ out)
{
    const int key = blockIdx.x;
    const int count = hist[key];
    if (count == 0) return;
    const int base = offs[key];
    const int wave = threadIdx.x >> 6;
    const int lane = threadIdx.x & 63;

    const bool isCtx = key >= NPAIRS;
    const int pair = isCtx ? key - NPAIRS : key;
    const unsigned short* Tb  = (isCtx ? Tc : Tw) + (size_t)pair * TPAIR;
    const unsigned short* g1t = isCtx ? g1c : g1w;

    // B fragments (T slice): 4 x 16B/lane, coalesced, loaded once per wave.
    const short8 b0 = *(const short8*)(Tb + 0 * 512 + lane * 8);
    const short8 b1 = *(const short8*)(Tb + 1 * 512 + lane * 8);
    const short8 b2 = *(const short8*)(Tb + 2 * 512 + lane * 8);
    const short8 b3 = *(const short8*)(Tb + 3 * 512 + lane * 8);

    const int l15 = lane & 15;
    const int kg  = lane >> 4;            // k-octet / D row group
    const int sel = (lane >> 3) & 1;      // A row 0-7 -> lookup0, 8-15 -> lookup1
    const int am  = lane & 7;             // A row's m within lookup

    const int ntile = (count + 1) >> 1;
    for (int jt = wave; jt < ntile; jt += 4) {
        const int j0 = 2 * jt;
        const bool has2 = (j0 + 1) < count;
        const int lid0 = __builtin_amdgcn_readfirstlane(grouped[base + j0]);
        const int lid1 = has2 ? __builtin_amdgcn_readfirstlane(grouped[base + j0 + 1]) : lid0;
        const int idx0 = __builtin_amdgcn_readfirstlane(
            lid0 < NWORD ? widx[lid0] : cidx[lid0 - NWORD]);
        const int idx1 = __builtin_amdgcn_readfirstlane(
            lid1 < NWORD ? widx[lid1] : cidx[lid1 - NWORD]);
        const int i1_0 = idx0 / (NFAC * NFAC);
        const int i1_1 = idx1 / (NFAC * NFAC);

        // A fragment: lane reads 8 consecutive r's of g1[i1][m] (16B).
        const unsigned short* pa =
            g1t + (sel ? i1_1 : i1_0) * 256 + am * 32 + kg * 8;
        const short8 a = *(const short8*)pa;

        const f32x4v z = {0.f, 0.f, 0.f, 0.f};
        const f32x4v d0 = __builtin_amdgcn_mfma_f32_16x16x32_bf16(a, b0, z, 0, 0, 0);
        const f32x4v d1 = __builtin_amdgcn_mfma_f32_16x16x32_bf16(a, b1, z, 0, 0, 0);
        const f32x4v d2 = __builtin_amdgcn_mfma_f32_16x16x32_bf16(a, b2, z, 0, 0, 0);
        const f32x4v d3 = __builtin_amdgcn_mfma_f32_16x16x32_bf16(a, b3, z, 0, 0, 0);

        float* o0 = out + (size_t)lid0 * 512;
        float* o1 = out + (size_t)lid1 * 512;
        #pragma unroll
        for (int q = 0; q < 4; ++q) {
            const int row = kg * 4 + q;           // 0..15: (lookup, m)
            const int mm = row & 7;
            float* ob = (row >= 8) ? o1 : o0;
            if (row < 8 || has2) {
                ob[mm * 64 +  0 + l15] = d0[q];
                ob[mm * 64 + 16 + l15] = d1[q];
                ob[mm * 64 + 32 + l15] = d2[q];
                ob[mm * 64 + 48 + l15] = d3[q];
            }
        }
    }
}

// ---------------- fallback: fully fused f32 (tiny ws) ----------------

__global__ __launch_bounds__(512) void tt_fused(
    const int* __restrict__ word_idx, const int* __restrict__ ctx_idx,
    const float* __restrict__ w1, const float* __restrict__ w2, const float* __restrict__ w3,
    const float* __restrict__ c1, const float* __restrict__ c2, const float* __restrict__ c3,
    float* __restrict__ out)
{
    const int b = blockIdx.x;
    int idx; const float *k1, *k2, *k3; float* o;
    if (b < NWORD) { idx = word_idx[b]; k1 = w1; k2 = w2; k3 = w3; o = out + (size_t)b * 512; }
    else { const int c = b - NWORD; idx = ctx_idx[c]; k1 = c1; k2 = c2; k3 = c3;
           o = out + (size_t)(NWORD + c) * 512; }
    const int i3 = idx % NFAC;
    const int rem = idx / NFAC;
    const int i2 = rem % NFAC;
    const int i1 = rem / NFAC;

    __shared__ float g3s[256];
    __shared__ float g1s[256];
    __shared__ float Ts[TPAIR];
    const int t = threadIdx.x;
    if (t < 256) g3s[t] = k3[i3 * 256 + t];
    else         g1s[t - 256] = k1[i1 * 256 + (t - 256)];
    __syncthreads();

    {
        const int e0 = t * 4;
        const int r = e0 >> 6, n = (e0 >> 3) & 7, p0 = e0 & 7;
        const float* g2row = k2 + i2 * 8192 + r * 256 + n * 32;
        float acc[4] = {0.f,0.f,0.f,0.f};
        #pragma unroll
        for (int s = 0; s < 32; ++s) {
            const float v = g2row[s];
            #pragma unroll
            for (int j = 0; j < 4; ++j) acc[j] += v * g3s[s * 8 + p0 + j];
        }
        reinterpret_cast<float4*>(Ts + e0)[0] = make_float4(acc[0], acc[1], acc[2], acc[3]);
    }
    __syncthreads();

    const int m = t >> 6, np = t & 63;
    float acc = 0.f;
    #pragma unroll
    for (int r = 0; r < 32; ++r)
        acc += g1s[m * 32 + r] * Ts[r * 64 + np];
    o[m * 64 + np] = acc;
}

extern "C" void kernel_launch(void* const* d_in, const int* in_sizes, int n_in,
                              void* d_out, int out_size, void* d_ws, size_t ws_size,
                              hipStream_t stream) {
    const int*   widx = (const int*)d_in[0];
    const int*   cidx = (const int*)d_in[1];
    const float* w1   = (const float*)d_in[2];
    const float* w2   = (const float*)d_in[3];
    const float* w3   = (const float*)d_in[4];
    const float* c1   = (const float*)d_in[5];
    const float* c2   = (const float*)d_in[6];
    const float* c3   = (const float*)d_in[7];
    float* out = (float*)d_out;

    // ws layout (bytes): Tw_bf, Tc_bf (2 x 10,240,000), g1w_bf, g1c_bf (2 x 25,600),
    // hist/offs/cursor (3 x 20,000), grouped (360,448)
    const size_t tbf_bytes = (size_t)NPAIRS * TPAIR * sizeof(unsigned short);
    const size_t need = 2 * tbf_bytes + 2 * 12800 * sizeof(unsigned short)
                      + (size_t)(3 * NKEYS + NLOOK) * sizeof(int);

    if (ws_size >= need) {
        unsigned short* Twb = (unsigned short*)d_ws;
        unsigned short* Tcb = Twb + (size_t)NPAIRS * TPAIR;
        unsigned short* g1wb = Tcb + (size_t)NPAIRS * TPAIR;
        unsigned short* g1cb = g1wb + 12800;
        int* hist    = (int*)(g1cb + 12800);
        int* offs    = hist + NKEYS;
        int* cursor  = offs + NKEYS;
        int* grouped = cursor + NKEYS;

        tt_zero<<<(NKEYS + 255) / 256, 256, 0, stream>>>(hist);
        tt_hist<<<(NLOOK + 255) / 256, 256, 0, stream>>>(widx, cidx, hist);
        tt_scan<<<1, 1024, 0, stream>>>(hist, offs, cursor);
        tt_scatter<<<(NLOOK + 255) / 256, 256, 0, stream>>>(widx, cidx, cursor, grouped);
        tt_cvt_g1<<<100, 256, 0, stream>>>(w1, c1, g1wb, g1cb);
        tt_precompute_bf<<<2 * NPAIRS, 256, 0, stream>>>(w2, w3, c2, c3, Twb, Tcb);
        tt_group_mfma<<<NKEYS, 256, 0, stream>>>(grouped, hist, offs, widx, cidx,
                                                 g1wb, g1cb, Twb, Tcb, out);
    } else {
        tt_fused<<<NLOOK, 512, 0, stream>>>(widx, cidx, w1, w2, w3, c1, c2, c3, out);
    }
}

// Round 7
// 84.054 us; speedup vs baseline: 1.9076x; 1.1938x over previous
//
#include <hip/hip_runtime.h>

// TT embedding gather, vocab 125000 = 50*50*50, emb 512 = 8*8*8.
// out[m,n,p] = sum_{r,s} g1[m,r] g2[r,n,s] g3[s,p]
// Pipeline (4 graph nodes):
//   1. hipMemsetAsync(hist)
//   2. tt_bucket: per lookup, key=(table, i2*50+i3); pos=atomicAdd(hist[key]);
//      bucket[key*MAXC+pos] = lid | (i1<<17)   (i1 pre-resolved: one less dependent load)
//   3. tt_precompute_bf: T[key][r][np]=sum_s g2 g3 -> bf16 in COLUMN-PERMUTED MFMA
//      B-frag layout (block c holds np=4j+c), staged via LDS, coalesced 16B stores;
//      +100 blocks convert g1 tables to bf16.
//   4. tt_group_mfma: one block (4 waves) per key; B-frags (4KB slice) in 16 VGPRs,
//      per tile (2 lookups): 1 bucket load -> 1 dwordx4 A-load -> 4x mfma 16x16x32_bf16
//      -> 4x float4 nontemporal stores (np=4*l15+c contiguous per lane).
// D mapping (m89-verified): col=lane&15, row=(lane>>4)*4+reg.

#define NFAC 50
#define TPAIR 2048
#define NPAIRS 2500
#define NKEYS 5000
#define MAXC 192
#define NWORD 8192
#define NCTX  81920
#define NLOOK (NWORD + NCTX)

typedef short short8 __attribute__((ext_vector_type(8)));   // 8 bf16 (4 VGPRs)
typedef float f32x4v __attribute__((ext_vector_type(4)));

__device__ __forceinline__ unsigned short f2bf(float f) {   // RNE f32 -> bf16 bits
    unsigned u = __builtin_bit_cast(unsigned, f);
    u += 0x7FFFu + ((u >> 16) & 1u);
    return (unsigned short)(u >> 16);
}

__device__ __forceinline__ int pair_of(int idx) {
    const int i3 = idx % NFAC;
    const int i2 = (idx / NFAC) % NFAC;
    return i2 * NFAC + i3;
}

// ---------------- bucket scatter (replaces zero/hist/scan/scatter) ----------------

__global__ __launch_bounds__(256) void tt_bucket(
    const int* __restrict__ widx, const int* __restrict__ cidx,
    int* __restrict__ hist, unsigned* __restrict__ bucket)
{
    const int g = blockIdx.x * 256 + threadIdx.x;
    if (g >= NLOOK) return;
    const int idx = (g < NWORD) ? widx[g] : cidx[g - NWORD];
    const int key = (g < NWORD ? 0 : NPAIRS) + pair_of(idx);
    const int i1  = idx / (NFAC * NFAC);
    const int pos = atomicAdd(&hist[key], 1);
    if (pos < MAXC)
        bucket[(size_t)key * MAXC + pos] = (unsigned)g | ((unsigned)i1 << 17);
}

// ---------------- T precompute -> bf16, column-permuted B-frag layout ----------------
// flat(np, r) = (np&3)*512 + ((r>>3)*16 + (np>>2))*8 + (r&7)
// (lane l of frag c then reads contiguous Tb + c*512 + l*8)

__global__ __launch_bounds__(256) void tt_precompute_bf(
    const float* __restrict__ w2, const float* __restrict__ w3,
    const float* __restrict__ c2, const float* __restrict__ c3,
    const float* __restrict__ w1, const float* __restrict__ c1,
    unsigned short* __restrict__ Tw, unsigned short* __restrict__ Tc,
    unsigned short* __restrict__ g1w, unsigned short* __restrict__ g1c)
{
    int pair = blockIdx.x;
    if (pair >= 2 * NPAIRS) {                        // g1 bf16 conversion tail blocks
        const int g = (pair - 2 * NPAIRS) * 256 + threadIdx.x;   // 0..25599
        if (g < 12800) g1w[g] = f2bf(w1[g]);
        else if (g < 25600) g1c[g - 12800] = f2bf(c1[g - 12800]);
        return;
    }
    const float* core2; const float* core3; unsigned short* T;
    if (pair < NPAIRS) { core2 = w2; core3 = w3; T = Tw; }
    else { pair -= NPAIRS; core2 = c2; core3 = c3; T = Tc; }
    const int i2 = pair / NFAC, i3 = pair % NFAC;
    __shared__ float g3s[256];                       // g3[s][p]
    __shared__ unsigned short tl[TPAIR];             // staged bf16 tile
    const int t = threadIdx.x;
    g3s[t] = core3[i3 * 256 + t];
    __syncthreads();
    const int r = t >> 3, n = t & 7;
    const float* g2row = core2 + i2 * 8192 + r * 256 + n * 32;
    float acc[8] = {0.f,0.f,0.f,0.f,0.f,0.f,0.f,0.f};
    #pragma unroll
    for (int s4 = 0; s4 < 8; ++s4) {
        const float4 v = reinterpret_cast<const float4*>(g2row)[s4];
        const float vv[4] = {v.x, v.y, v.z, v.w};
        #pragma unroll
        for (int j = 0; j < 4; ++j) {
            const int s = s4 * 4 + j;
            #pragma unroll
            for (int p = 0; p < 8; ++p)
                acc[p] += vv[j] * g3s[s * 8 + p];
        }
    }
    #pragma unroll
    for (int p = 0; p < 8; ++p) {
        const int np = n * 8 + p;
        const int flat = (np & 3) * 512 + ((r >> 3) * 16 + (np >> 2)) * 8 + (r & 7);
        tl[flat] = f2bf(acc[p]);
    }
    __syncthreads();
    uint4* dst = reinterpret_cast<uint4*>(T + (size_t)pair * TPAIR);
    dst[t] = reinterpret_cast<const uint4*>(tl)[t];  // coalesced 16B/thread
}

// ---------------- MFMA group kernel ----------------

__global__ __launch_bounds__(256, 8) void tt_group_mfma(
    const unsigned* __restrict__ bucket, const int* __restrict__ hist,
    const unsigned short* __restrict__ g1w, const unsigned short* __restrict__ g1c,
    const unsigned short* __restrict__ Tw, const unsigned short* __restrict__ Tc,
    float* __restrict__ out)
{
    const int key = blockIdx.x;
    int count = hist[key];
    if (count == 0) return;
    if (count > MAXC) count = MAXC;
    const int wave = threadIdx.x >> 6;
    const int lane = threadIdx.x & 63;

    const bool isCtx = key >= NPAIRS;
    const int pair = isCtx ? key - NPAIRS : key;
    const unsigned short* Tb  = (isCtx ? Tc : Tw) + (size_t)pair * TPAIR;
    const unsigned short* g1t = isCtx ? g1c : g1w;
    const unsigned* kb = bucket + (size_t)key * MAXC;

    // B fragments: 4 x 16B/lane, coalesced, loaded once per wave.
    const short8 b0 = *(const short8*)(Tb + 0 * 512 + lane * 8);
    const short8 b1 = *(const short8*)(Tb + 1 * 512 + lane * 8);
    const short8 b2 = *(const short8*)(Tb + 2 * 512 + lane * 8);
    const short8 b3 = *(const short8*)(Tb + 3 * 512 + lane * 8);

    const int l15 = lane & 15;
    const int kg  = lane >> 4;            // A k-octet / D row group
    const int sel = (lane >> 3) & 1;      // A rows 0-7 -> lookup0, 8-15 -> lookup1
    const int am  = lane & 7;             // m within lookup

    const int ntile = (count + 1) >> 1;
    for (int jt = wave; jt < ntile; jt += 4) {
        const int j0 = 2 * jt;
        const bool has2 = (j0 + 1) < count;
        const unsigned pk0 = __builtin_amdgcn_readfirstlane(kb[j0]);
        const unsigned pk1 = has2 ? __builtin_amdgcn_readfirstlane(kb[j0 + 1]) : pk0;
        const int lid0 = pk0 & 0x1FFFF, i10 = pk0 >> 17;
        const int lid1 = pk1 & 0x1FFFF, i11 = pk1 >> 17;

        const short8 a = *(const short8*)(g1t + (sel ? i11 : i10) * 256 + am * 32 + kg * 8);

        const f32x4v z = {0.f, 0.f, 0.f, 0.f};
        const f32x4v d0 = __builtin_amdgcn_mfma_f32_16x16x32_bf16(a, b0, z, 0, 0, 0);
        const f32x4v d1 = __builtin_amdgcn_mfma_f32_16x16x32_bf16(a, b1, z, 0, 0, 0);
        const f32x4v d2 = __builtin_amdgcn_mfma_f32_16x16x32_bf16(a, b2, z, 0, 0, 0);
        const f32x4v d3 = __builtin_amdgcn_mfma_f32_16x16x32_bf16(a, b3, z, 0, 0, 0);

        float* o0 = out + (size_t)lid0 * 512;
        float* o1 = out + (size_t)lid1 * 512;
        #pragma unroll
        for (int q = 0; q < 4; ++q) {
            const int row = kg * 4 + q;          // 0..15 = (lookup, m)
            const int mm = row & 7;
            float* ob = (row >= 8) ? o1 : o0;
            if (row < 8 || has2) {
                f32x4v v; v[0] = d0[q]; v[1] = d1[q]; v[2] = d2[q]; v[3] = d3[q];
                __builtin_nontemporal_store(v, (f32x4v*)(ob + mm * 64 + 4 * l15));
            }
        }
    }
}

// ---------------- fallback: fully fused f32 (tiny ws) ----------------

__global__ __launch_bounds__(512) void tt_fused(
    const int* __restrict__ word_idx, const int* __restrict__ ctx_idx,
    const float* __restrict__ w1, const float* __restrict__ w2, const float* __restrict__ w3,
    const float* __restrict__ c1, const float* __restrict__ c2, const float* __restrict__ c3,
    float* __restrict__ out)
{
    const int b = blockIdx.x;
    int idx; const float *k1, *k2, *k3; float* o;
    if (b < NWORD) { idx = word_idx[b]; k1 = w1; k2 = w2; k3 = w3; o = out + (size_t)b * 512; }
    else { const int c = b - NWORD; idx = ctx_idx[c]; k1 = c1; k2 = c2; k3 = c3;
           o = out + (size_t)(NWORD + c) * 512; }
    const int i3 = idx % NFAC;
    const int rem = idx / NFAC;
    const int i2 = rem % NFAC;
    const int i1 = rem / NFAC;

    __shared__ float g3s[256];
    __shared__ float g1s[256];
    __shared__ float Ts[TPAIR];
    const int t = threadIdx.x;
    if (t < 256) g3s[t] = k3[i3 * 256 + t];
    else         g1s[t - 256] = k1[i1 * 256 + (t - 256)];
    __syncthreads();

    {
        const int e0 = t * 4;
        const int r = e0 >> 6, n = (e0 >> 3) & 7, p0 = e0 & 7;
        const float* g2row = k2 + i2 * 8192 + r * 256 + n * 32;
        float acc[4] = {0.f,0.f,0.f,0.f};
        #pragma unroll
        for (int s = 0; s < 32; ++s) {
            const float v = g2row[s];
            #pragma unroll
            for (int j = 0; j < 4; ++j) acc[j] += v * g3s[s * 8 + p0 + j];
        }
        reinterpret_cast<float4*>(Ts + e0)[0] = make_float4(acc[0], acc[1], acc[2], acc[3]);
    }
    __syncthreads();

    const int m = t >> 6, np = t & 63;
    float acc = 0.f;
    #pragma unroll
    for (int r = 0; r < 32; ++r)
        acc += g1s[m * 32 + r] * Ts[r * 64 + np];
    o[m * 64 + np] = acc;
}

extern "C" void kernel_launch(void* const* d_in, const int* in_sizes, int n_in,
                              void* d_out, int out_size, void* d_ws, size_t ws_size,
                              hipStream_t stream) {
    const int*   widx = (const int*)d_in[0];
    const int*   cidx = (const int*)d_in[1];
    const float* w1   = (const float*)d_in[2];
    const float* w2   = (const float*)d_in[3];
    const float* w3   = (const float*)d_in[4];
    const float* c1   = (const float*)d_in[5];
    const float* c2   = (const float*)d_in[6];
    const float* c3   = (const float*)d_in[7];
    float* out = (float*)d_out;

    // ws layout: Tw,Tc bf16 (2 x 10,240,000 B), g1w,g1c bf16 (2 x 25,600 B),
    //            hist (20,000 B), bucket (5000*192*4 = 3,840,000 B)
    const size_t t_half = (size_t)NPAIRS * TPAIR;                 // ushort elems
    const size_t need = 2 * t_half * 2 + 2 * 25600 + NKEYS * 4
                      + (size_t)NKEYS * MAXC * 4;

    if (ws_size >= need) {
        unsigned short* Twb  = (unsigned short*)d_ws;
        unsigned short* Tcb  = Twb + t_half;
        unsigned short* g1wb = Tcb + t_half;
        unsigned short* g1cb = g1wb + 12800;
        int*      hist   = (int*)(g1cb + 12800);
        unsigned* bucket = (unsigned*)(hist + NKEYS);

        hipMemsetAsync(hist, 0, NKEYS * sizeof(int), stream);
        tt_bucket<<<(NLOOK + 255) / 256, 256, 0, stream>>>(widx, cidx, hist, bucket);
        tt_precompute_bf<<<2 * NPAIRS + 100, 256, 0, stream>>>(
            w2, w3, c2, c3, w1, c1, Twb, Tcb, g1wb, g1cb);
        tt_group_mfma<<<NKEYS, 256, 0, stream>>>(bucket, hist, g1wb, g1cb, Twb, Tcb, out);
    } else {
        tt_fused<<<NLOOK, 512, 0, stream>>>(widx, cidx, w1, w2, w3, c1, c2, c3, out);
    }
}

// Round 8
// 64.999 us; speedup vs baseline: 2.4668x; 1.2931x over previous
//
#include <hip/hip_runtime.h>

// TT embedding gather, vocab 125000 = 50*50*50, emb 512 = 8*8*8.
// out[m,n,p] = sum_{r,s} g1[m,r] g2[r,n,s] g3[s,p]
// Pipeline (3 graph nodes):
//   1. hipMemsetAsync(hist, 0)
//   2. tt_bucket: per lookup, key=(table, i2*50+i3); pos=atomicAdd(hist[key]);
//      bucket[key*MAXC+pos] = lid | (i1<<17).  +100 tail blocks convert g1 -> bf16.
//   3. tt_group_fused: one block (4 waves) per key.
//      Phase A (256 threads): T[r][np] = sum_s g2[r,n,s] g3[s,p] in f32,
//        rounded to bf16 into LDS in COLUMN-PERMUTED MFMA B-frag layout
//        flat(np,r) = (np&3)*512 + ((r>>3)*16 + (np>>2))*8 + (r&7).
//      Phase B: each wave ds_read_b128 x4 -> B-frags in 16 VGPRs; per tile
//        (2 lookups): bucket load -> 1 dwordx4 A-load (g1 bf16 rows) ->
//        4x mfma_f32_16x16x32_bf16 -> 4x float4 nontemporal stores.
//      Block order: XCD-chunked bijective swizzle (5000%8==0) composed with
//      word/ctx interleave (load balance + same-i2 g2-slice L2 reuse).
// D mapping (m89-verified): col=lane&15, row=(lane>>4)*4+reg.

#define NFAC 50
#define TPAIR 2048
#define NPAIRS 2500
#define NKEYS 5000
#define MAXC 192
#define NWORD 8192
#define NCTX  81920
#define NLOOK (NWORD + NCTX)
#define NBB   ((NLOOK + 255) / 256)          // 352 (exact: 352*256 == NLOOK)

typedef short short8 __attribute__((ext_vector_type(8)));   // 8 bf16 (4 VGPRs)
typedef float f32x4v __attribute__((ext_vector_type(4)));

__device__ __forceinline__ unsigned short f2bf(float f) {   // RNE f32 -> bf16 bits
    unsigned u = __builtin_bit_cast(unsigned, f);
    u += 0x7FFFu + ((u >> 16) & 1u);
    return (unsigned short)(u >> 16);
}

__device__ __forceinline__ int pair_of(int idx) {
    const int i3 = idx % NFAC;
    const int i2 = (idx / NFAC) % NFAC;
    return i2 * NFAC + i3;
}

// ---------------- bucket scatter + g1 bf16 conversion ----------------

__global__ __launch_bounds__(256) void tt_bucket(
    const int* __restrict__ widx, const int* __restrict__ cidx,
    const float* __restrict__ w1, const float* __restrict__ c1,
    int* __restrict__ hist, unsigned* __restrict__ bucket,
    unsigned short* __restrict__ g1w, unsigned short* __restrict__ g1c)
{
    const int b = blockIdx.x;
    if (b >= NBB) {                                  // g1 bf16 conversion tail
        const int g = (b - NBB) * 256 + threadIdx.x; // 0..25599
        if (g < 12800) g1w[g] = f2bf(w1[g]);
        else if (g < 25600) g1c[g - 12800] = f2bf(c1[g - 12800]);
        return;
    }
    const int g = b * 256 + threadIdx.x;             // < NLOOK exactly
    const int idx = (g < NWORD) ? widx[g] : cidx[g - NWORD];
    const int key = (g < NWORD ? 0 : NPAIRS) + pair_of(idx);
    const int i1  = idx / (NFAC * NFAC);
    const int pos = atomicAdd(&hist[key], 1);
    if (pos < MAXC)
        bucket[(size_t)key * MAXC + pos] = (unsigned)g | ((unsigned)i1 << 17);
}

// ---------------- fused group kernel ----------------

__global__ __launch_bounds__(256, 8) void tt_group_fused(
    const unsigned* __restrict__ bucket, const int* __restrict__ hist,
    const unsigned short* __restrict__ g1w, const unsigned short* __restrict__ g1c,
    const float* __restrict__ w2, const float* __restrict__ w3,
    const float* __restrict__ c2, const float* __restrict__ c3,
    float* __restrict__ out)
{
    // XCD-chunked bijective swizzle (each XCD: 625 contiguous swz) then
    // word/ctx interleave (even swz -> word key, odd -> ctx key).
    const int B = blockIdx.x;
    const int swz = (B & 7) * (NKEYS / 8) + (B >> 3);
    const int key = (swz & 1) ? ((swz >> 1) + NPAIRS) : (swz >> 1);

    int count = hist[key];
    if (count == 0) return;
    if (count > MAXC) count = MAXC;

    const bool isCtx = key >= NPAIRS;
    const int pair = isCtx ? key - NPAIRS : key;
    const float* core2 = isCtx ? c2 : w2;
    const float* core3 = isCtx ? c3 : w3;
    const unsigned short* g1t = isCtx ? g1c : g1w;
    const unsigned* kb = bucket + (size_t)key * MAXC;
    const int i2 = pair / NFAC, i3 = pair % NFAC;

    __shared__ float g3s[256];                       // g3[s][p]
    __shared__ unsigned short tl[TPAIR];             // bf16 T tile, B-frag layout
    const int t = threadIdx.x;

    // ---- Phase A: T tile -> LDS ----
    g3s[t] = core3[i3 * 256 + t];
    __syncthreads();
    {
        const int r = t >> 3, n = t & 7;
        const float* g2row = core2 + i2 * 8192 + r * 256 + n * 32;
        float acc[8] = {0.f,0.f,0.f,0.f,0.f,0.f,0.f,0.f};
        #pragma unroll
        for (int s4 = 0; s4 < 8; ++s4) {
            const float4 v = reinterpret_cast<const float4*>(g2row)[s4];
            const float vv[4] = {v.x, v.y, v.z, v.w};
            #pragma unroll
            for (int j = 0; j < 4; ++j) {
                const int s = s4 * 4 + j;
                #pragma unroll
                for (int p = 0; p < 8; ++p)
                    acc[p] += vv[j] * g3s[s * 8 + p];   // uniform addr: broadcast
            }
        }
        #pragma unroll
        for (int p = 0; p < 8; ++p) {
            const int np = n * 8 + p;
            const int flat = (np & 3) * 512 + ((r >> 3) * 16 + (np >> 2)) * 8 + (r & 7);
            tl[flat] = f2bf(acc[p]);
        }
    }
    __syncthreads();

    // ---- Phase B: MFMA over the group's lookups ----
    const int wave = t >> 6;
    const int lane = t & 63;
    const short8 b0 = *reinterpret_cast<const short8*>(&tl[0 * 512 + lane * 8]);
    const short8 b1 = *reinterpret_cast<const short8*>(&tl[1 * 512 + lane * 8]);
    const short8 b2 = *reinterpret_cast<const short8*>(&tl[2 * 512 + lane * 8]);
    const short8 b3 = *reinterpret_cast<const short8*>(&tl[3 * 512 + lane * 8]);

    const int l15 = lane & 15;
    const int kg  = lane >> 4;            // A k-octet / D row group
    const int sel = (lane >> 3) & 1;      // A rows 0-7 -> lookup0, 8-15 -> lookup1
    const int am  = lane & 7;             // m within lookup

    const int ntile = (count + 1) >> 1;
    for (int jt = wave; jt < ntile; jt += 4) {
        const int j0 = 2 * jt;
        const bool has2 = (j0 + 1) < count;
        const unsigned pk0 = __builtin_amdgcn_readfirstlane(kb[j0]);
        const unsigned pk1 = has2 ? __builtin_amdgcn_readfirstlane(kb[j0 + 1]) : pk0;
        const int lid0 = pk0 & 0x1FFFF, i10 = pk0 >> 17;
        const int lid1 = pk1 & 0x1FFFF, i11 = pk1 >> 17;

        const short8 a = *reinterpret_cast<const short8*>(
            g1t + (sel ? i11 : i10) * 256 + am * 32 + kg * 8);

        const f32x4v z = {0.f, 0.f, 0.f, 0.f};
        const f32x4v d0 = __builtin_amdgcn_mfma_f32_16x16x32_bf16(a, b0, z, 0, 0, 0);
        const f32x4v d1 = __builtin_amdgcn_mfma_f32_16x16x32_bf16(a, b1, z, 0, 0, 0);
        const f32x4v d2 = __builtin_amdgcn_mfma_f32_16x16x32_bf16(a, b2, z, 0, 0, 0);
        const f32x4v d3 = __builtin_amdgcn_mfma_f32_16x16x32_bf16(a, b3, z, 0, 0, 0);

        float* o0 = out + (size_t)lid0 * 512;
        float* o1 = out + (size_t)lid1 * 512;
        #pragma unroll
        for (int q = 0; q < 4; ++q) {
            const int row = kg * 4 + q;          // 0..15 = (lookup, m)
            const int mm = row & 7;
            float* ob = (row >= 8) ? o1 : o0;
            if (row < 8 || has2) {
                f32x4v v; v[0] = d0[q]; v[1] = d1[q]; v[2] = d2[q]; v[3] = d3[q];
                __builtin_nontemporal_store(v, (f32x4v*)(ob + mm * 64 + 4 * l15));
            }
        }
    }
}

// ---------------- fallback: fully fused f32 (tiny ws) ----------------

__global__ __launch_bounds__(512) void tt_fused(
    const int* __restrict__ word_idx, const int* __restrict__ ctx_idx,
    const float* __restrict__ w1, const float* __restrict__ w2, const float* __restrict__ w3,
    const float* __restrict__ c1, const float* __restrict__ c2, const float* __restrict__ c3,
    float* __restrict__ out)
{
    const int b = blockIdx.x;
    int idx; const float *k1, *k2, *k3; float* o;
    if (b < NWORD) { idx = word_idx[b]; k1 = w1; k2 = w2; k3 = w3; o = out + (size_t)b * 512; }
    else { const int c = b - NWORD; idx = ctx_idx[c]; k1 = c1; k2 = c2; k3 = c3;
           o = out + (size_t)(NWORD + c) * 512; }
    const int i3 = idx % NFAC;
    const int rem = idx / NFAC;
    const int i2 = rem % NFAC;
    const int i1 = rem / NFAC;

    __shared__ float g3s[256];
    __shared__ float g1s[256];
    __shared__ float Ts[TPAIR];
    const int t = threadIdx.x;
    if (t < 256) g3s[t] = k3[i3 * 256 + t];
    else         g1s[t - 256] = k1[i1 * 256 + (t - 256)];
    __syncthreads();

    {
        const int e0 = t * 4;
        const int r = e0 >> 6, n = (e0 >> 3) & 7, p0 = e0 & 7;
        const float* g2row = k2 + i2 * 8192 + r * 256 + n * 32;
        float acc[4] = {0.f,0.f,0.f,0.f};
        #pragma unroll
        for (int s = 0; s < 32; ++s) {
            const float v = g2row[s];
            #pragma unroll
            for (int j = 0; j < 4; ++j) acc[j] += v * g3s[s * 8 + p0 + j];
        }
        reinterpret_cast<float4*>(Ts + e0)[0] = make_float4(acc[0], acc[1], acc[2], acc[3]);
    }
    __syncthreads();

    const int m = t >> 6, np = t & 63;
    float acc = 0.f;
    #pragma unroll
    for (int r = 0; r < 32; ++r)
        acc += g1s[m * 32 + r] * Ts[r * 64 + np];
    o[m * 64 + np] = acc;
}

extern "C" void kernel_launch(void* const* d_in, const int* in_sizes, int n_in,
                              void* d_out, int out_size, void* d_ws, size_t ws_size,
                              hipStream_t stream) {
    const int*   widx = (const int*)d_in[0];
    const int*   cidx = (const int*)d_in[1];
    const float* w1   = (const float*)d_in[2];
    const float* w2   = (const float*)d_in[3];
    const float* w3   = (const float*)d_in[4];
    const float* c1   = (const float*)d_in[5];
    const float* c2   = (const float*)d_in[6];
    const float* c3   = (const float*)d_in[7];
    float* out = (float*)d_out;

    // ws layout: g1w,g1c bf16 (2 x 25,600 B), hist (20,000 B),
    //            bucket (5000*192*4 = 3,840,000 B)  => ~3.9 MB total
    const size_t need = 2 * 25600 + NKEYS * 4 + (size_t)NKEYS * MAXC * 4;

    if (ws_size >= need) {
        unsigned short* g1wb = (unsigned short*)d_ws;
        unsigned short* g1cb = g1wb + 12800;
        int*      hist   = (int*)(g1cb + 12800);
        unsigned* bucket = (unsigned*)(hist + NKEYS);

        hipMemsetAsync(hist, 0, NKEYS * sizeof(int), stream);
        tt_bucket<<<NBB + 100, 256, 0, stream>>>(widx, cidx, w1, c1,
                                                 hist, bucket, g1wb, g1cb);
        tt_group_fused<<<NKEYS, 256, 0, stream>>>(bucket, hist, g1wb, g1cb,
                                                  w2, w3, c2, c3, out);
    } else {
        tt_fused<<<NLOOK, 512, 0, stream>>>(widx, cidx, w1, w2, w3, c1, c2, c3, out);
    }
}